// Round 8
// baseline (281.580 us; speedup 1.0000x reference)
//
#include <hip/hip_runtime.h>
#include <cstddef>
#include <cstdint>

#define IN_DIM 256
#define H_DIM  128
#define C_DIM  40
#define BM     128
#define LDAH   132   // ushort stride of half-K A-slab rows / h-tile rows (264 B)
#define XA_C   32    // split-x: xa cols (64 B row, 1 sector)
#define XB_C   8     // split-x: xb cols (16 B row, L2-hot)
#define STEP   512   // ushorts per ks slab of b_frag/w2f: 64 lanes x 8 bf16

typedef short bf16x8 __attribute__((ext_vector_type(8)));
typedef float f32x16 __attribute__((ext_vector_type(16)));
typedef uint  u32x4  __attribute__((ext_vector_type(4)));

__device__ __forceinline__ ushort f2bf(float f) {   // RNE fp32 -> bf16
  uint u = __builtin_bit_cast(uint, f);
  u += 0x7fffu + ((u >> 16) & 1u);
  return (ushort)(u >> 16);
}
__device__ __forceinline__ float bf2f(uint s) {     // low 16 bits -> f32
  uint u = s << 16;
  return __builtin_bit_cast(float, u);
}
// packed fp32x2 -> bf16x2 (HW cvt if available; manual RNE fallback)
__device__ __forceinline__ uint pack2bf(float a, float b) {
#if __has_builtin(__builtin_amdgcn_cvt_pk_bf16_f32)
  typedef __bf16 bf16v2 __attribute__((ext_vector_type(2)));
  bf16v2 r = __builtin_amdgcn_cvt_pk_bf16_f32(a, b);
  return __builtin_bit_cast(uint, r);
#else
  return (uint)f2bf(a) | ((uint)f2bf(b) << 16);
#endif
}

// ---------------------------------------------------------------------------
// Setup (one launch):
//  tid < E:     CSR row_ptr via boundary scan of sorted dst (coalesced O(E)).
//  next 4096:   W1 -> b_frag (MFMA B-fragment order for GEMM1).
//  next 1024:   W2 -> w2f   (MFMA B-fragment order for GEMM2, zero-pad n>=40).
// b_frag[tn][ks][l] (ushort8) = W1[16ks + (l>>5)*8 + j][32tn + (l&31)]
// w2f[kb][tn][l]    (ushort8) = W2[16kb + (l>>5)*8 + j][32tn + (l&31)] (0 pad)
// ---------------------------------------------------------------------------
__global__ void setup_kernel(const int* __restrict__ dst, int E,
                             int* __restrict__ row_ptr, int N,
                             const float* __restrict__ W1,
                             const float* __restrict__ W2,
                             ushort* __restrict__ b_frag,
                             ushort* __restrict__ w2f) {
  int tid = blockIdx.x * blockDim.x + threadIdx.x;
  if (tid < E) {
    int d1 = dst[tid];
    int d0 = (tid == 0) ? -1 : dst[tid - 1];
    for (int v = d0 + 1; v <= d1; ++v) row_ptr[v] = tid;
    if (tid == E - 1)
      for (int v = d1 + 1; v <= N; ++v) row_ptr[v] = E;
    return;
  }
  int u = tid - E;
  if (u < 4096) {                               // W1 -> b_frag fragment order
    int l = u & 63, ks = (u >> 6) & 15, tn = u >> 10;
    int n  = 32 * tn + (l & 31);
    int k0 = ks * 16 + ((l >> 5) << 3);
    ushort r[8];
#pragma unroll
    for (int j = 0; j < 8; ++j) r[j] = f2bf(W1[(k0 + j) * H_DIM + n]);
    *(uint4*)(b_frag + u * 8) = *(uint4*)r;
    return;
  }
  u -= 4096;
  if (u < 1024) {                               // W2 -> w2f fragment order
    int l = u & 63, kt = u >> 6;                // kt = kb*2 + tn
    int tn = kt & 1, kb = kt >> 1;
    int n  = 32 * tn + (l & 31);
    int k0 = kb * 16 + ((l >> 5) << 3);
    ushort r[8];
#pragma unroll
    for (int j = 0; j < 8; ++j)
      r[j] = (n < C_DIM) ? f2bf(W2[(k0 + j) * C_DIM + n]) : (ushort)0;
    *(uint4*)(w2f + u * 8) = *(uint4*)r;
  }
}

// ---------------------------------------------------------------------------
// Fused dense MLP -> split-layout z0 (z0a [N][32] bf16 + z0b [N][8] bf16).
// Block 256 thr (4 waves), 33792 B LDS -> 4 blocks/CU, 16 waves/CU (4/SIMD).
// ZERO BARRIERS, wave-private slab of 32 x LDAH ushorts, staged in TWO
// K-halves (128 cols each) reusing the same slab: stage half -> 8 MFMA
// K-steps -> restage -> 8 steps. WAR/RAW on the slab is same-wave only
// (LDS aliasing keeps program order; MFMA operand waits drain the reads).
// Staging reads are fully coalesced: 64 lanes x float4 = 1 KB = 2 rows/instr.
// B (GEMM1) and W2 (GEMM2) fragments stream from L2-resident b_frag / w2f
// with depth-2 ping-pong. 4x the resident waves of R7 = the latency hiding
// the R6 counters (MfmaUtil 4.9 / VALU 8.3 / HBM 12.5, all idle) demanded.
// ---------------------------------------------------------------------------
__global__ __launch_bounds__(256, 4) void fused_dense_kernel(
    const float* __restrict__ feat, const ushort* __restrict__ b_frag,
    const ushort* __restrict__ w2f, ushort* __restrict__ z0a,
    ushort* __restrict__ z0b, int N) {
  __shared__ __align__(16) ushort smem[4 * 32 * LDAH];   // 33792 B

  const int t = threadIdx.x;
  const int w = t >> 6, l = t & 63;
  const int nb = blockIdx.x * BM;
  ushort* slab = smem + w * (32 * LDAH);          // this wave's private region

  f32x16 acc[4];
#pragma unroll
  for (int tn = 0; tn < 4; ++tn)
#pragma unroll
    for (int r = 0; r < 16; ++r) acc[tn][r] = 0.f;

  const ushort* bp = b_frag + l * 8;
  bf16x8 Bx[2][4];
#pragma unroll
  for (int tn = 0; tn < 4; ++tn)
    Bx[0][tn] = *(const bf16x8*)(bp + tn * (16 * STEP));

  const ushort* Abase = slab + (l & 31) * LDAH + ((l >> 5) << 3);

#pragma unroll
  for (int h = 0; h < 2; ++h) {
    // ---- stage K-half h: instr c covers rows {2c, 2c+1} fully contiguously
#pragma unroll
    for (int c = 0; c < 16; ++c) {
      int r2 = 2 * c + (l >> 5);
      int grow = nb + 32 * w + r2; if (grow >= N) grow = N - 1;
      float4 v = *(const float4*)(feat + (size_t)grow * IN_DIM + h * 128 + (l & 31) * 4);
      uint2 pk;
      pk.x = pack2bf(v.x, v.y);
      pk.y = pack2bf(v.z, v.w);
      *(uint2*)(slab + r2 * LDAH + (l & 31) * 4) = pk;
    }
    // ---- 8 MFMA K-steps on this half; B ping-pong continues across halves
#pragma unroll
    for (int kk = 0; kk < 8; ++kk) {
      const int ks = h * 8 + kk;
      const int c = ks & 1;
      if (ks < 15) {
#pragma unroll
        for (int tn = 0; tn < 4; ++tn)
          Bx[c ^ 1][tn] = *(const bf16x8*)(bp + tn * (16 * STEP) + (ks + 1) * STEP);
      }
      bf16x8 af = *(const bf16x8*)(Abase + kk * 16);
#pragma unroll
      for (int tn = 0; tn < 4; ++tn)
        acc[tn] = __builtin_amdgcn_mfma_f32_32x32x16_bf16(af, Bx[c][tn], acc[tn], 0, 0, 0);
    }
  }

  // ---- relu(h) -> own slab rows [nl][k], stride LDAH (aliases A slab; private)
#pragma unroll
  for (int tn = 0; tn < 4; ++tn) {
    int col = tn * 32 + (l & 31);
#pragma unroll
    for (int r = 0; r < 16; ++r) {
      int nl = (r & 3) + 8 * (r >> 2) + 4 * (l >> 5);
      float v = acc[tn][r];
      slab[nl * LDAH + col] = f2bf(v > 0.f ? v : 0.f);
    }
  }

  // ---- GEMM2: h-fragments from own slab, W2-fragments from global w2f (L2)
  f32x16 acc2[2];
#pragma unroll
  for (int tn = 0; tn < 2; ++tn)
#pragma unroll
    for (int r = 0; r < 16; ++r) acc2[tn][r] = 0.f;

  const ushort* Hbase = slab + (l & 31) * LDAH + ((l >> 5) << 3);
  const ushort* wp = w2f + l * 8;
#pragma unroll
  for (int kb = 0; kb < 8; ++kb) {
    bf16x8 af = *(const bf16x8*)(Hbase + kb * 16);
#pragma unroll
    for (int tn = 0; tn < 2; ++tn) {
      bf16x8 bfr = *(const bf16x8*)(wp + (kb * 2 + tn) * STEP);
      acc2[tn] = __builtin_amdgcn_mfma_f32_32x32x16_bf16(af, bfr, acc2[tn], 0, 0, 0);
    }
  }

  // ---- store split z0: cols 0..31 -> z0a, cols 32..39 -> z0b
#pragma unroll
  for (int r = 0; r < 16; ++r) {
    int node = nb + 32 * w + (r & 3) + 8 * (r >> 2) + 4 * (l >> 5);
    if (node < N) {
      z0a[(size_t)node * XA_C + (l & 31)] = f2bf(acc2[0][r]);
      if ((l & 31) < XB_C)
        z0b[(size_t)node * XB_C + (l & 31)] = f2bf(acc2[1][r]);
    }
  }
}

// ---------------------------------------------------------------------------
// SPMM (CSR, dst-sorted), split-x layout: xa [N][32] bf16 (64-B rows, exactly
// ONE sector per gathered row) + xb [N][8] bf16 (16-B rows, 1.6 MB, L2-hot,
// 4 rows/sector). One wave per node; lane = 8*h + j; j<4 -> xa quad j,
// j==4 -> xb, j>4 idle. Halves gather sector traffic vs 80-B rows.
// ---------------------------------------------------------------------------
__global__ __launch_bounds__(256) void spmm_kernel(
    const int* __restrict__ row_ptr, const int* __restrict__ esrc,
    const float* __restrict__ eval, const ushort* __restrict__ xa,
    const ushort* __restrict__ xb, ushort* __restrict__ za,
    ushort* __restrict__ zb, float* __restrict__ zf, int N, int out_f32) {
  int node = (blockIdx.x << 2) + (threadIdx.x >> 6);
  if (node >= N) return;
  const int lane = threadIdx.x & 63;
  const int h = lane >> 3;          // edge slot
  const int j = lane & 7;           // col oct (j<5 active)
  const bool act = (j < 5);

  int e   = row_ptr[node];
  int end = row_ptr[node + 1];

  float acc[8];
#pragma unroll
  for (int c = 0; c < 8; ++c) acc[c] = 0.f;

  // 16 edges per iteration: two independent gather chains
  for (; e + 16 <= end; e += 16) {
    int   s0 = esrc[e + h];
    int   s1 = esrc[e + 8 + h];
    float v0 = eval[e + h];
    float v1 = eval[e + 8 + h];
    if (act) {
      u32x4 a = (j < 4) ? *(const u32x4*)(xa + (size_t)s0 * XA_C + j * 8)
                        : *(const u32x4*)(xb + (size_t)s0 * XB_C);
      u32x4 b = (j < 4) ? *(const u32x4*)(xa + (size_t)s1 * XA_C + j * 8)
                        : *(const u32x4*)(xb + (size_t)s1 * XB_C);
      acc[0] = fmaf(v0, bf2f(a.x & 0xffffu), acc[0]);
      acc[1] = fmaf(v0, bf2f(a.x >> 16),     acc[1]);
      acc[2] = fmaf(v0, bf2f(a.y & 0xffffu), acc[2]);
      acc[3] = fmaf(v0, bf2f(a.y >> 16),     acc[3]);
      acc[4] = fmaf(v0, bf2f(a.z & 0xffffu), acc[4]);
      acc[5] = fmaf(v0, bf2f(a.z >> 16),     acc[5]);
      acc[6] = fmaf(v0, bf2f(a.w & 0xffffu), acc[6]);
      acc[7] = fmaf(v0, bf2f(a.w >> 16),     acc[7]);
      acc[0] = fmaf(v1, bf2f(b.x & 0xffffu), acc[0]);
      acc[1] = fmaf(v1, bf2f(b.x >> 16),     acc[1]);
      acc[2] = fmaf(v1, bf2f(b.y & 0xffffu), acc[2]);
      acc[3] = fmaf(v1, bf2f(b.y >> 16),     acc[3]);
      acc[4] = fmaf(v1, bf2f(b.z & 0xffffu), acc[4]);
      acc[5] = fmaf(v1, bf2f(b.z >> 16),     acc[5]);
      acc[6] = fmaf(v1, bf2f(b.w & 0xffffu), acc[6]);
      acc[7] = fmaf(v1, bf2f(b.w >> 16),     acc[7]);
    }
  }
  for (; e + 8 <= end; e += 8) {
    int   s = esrc[e + h];
    float v = eval[e + h];
    if (act) {
      u32x4 u = (j < 4) ? *(const u32x4*)(xa + (size_t)s * XA_C + j * 8)
                        : *(const u32x4*)(xb + (size_t)s * XB_C);
      acc[0] = fmaf(v, bf2f(u.x & 0xffffu), acc[0]);
      acc[1] = fmaf(v, bf2f(u.x >> 16),     acc[1]);
      acc[2] = fmaf(v, bf2f(u.y & 0xffffu), acc[2]);
      acc[3] = fmaf(v, bf2f(u.y >> 16),     acc[3]);
      acc[4] = fmaf(v, bf2f(u.z & 0xffffu), acc[4]);
      acc[5] = fmaf(v, bf2f(u.z >> 16),     acc[5]);
      acc[6] = fmaf(v, bf2f(u.w & 0xffffu), acc[6]);
      acc[7] = fmaf(v, bf2f(u.w >> 16),     acc[7]);
    }
  }
  if (e < end) {                    // tail: clamp slots past the end, weight 0
    int ei = e + h;
    int ec = ei < end ? ei : end - 1;
    int   s  = esrc[ec];
    float v0 = eval[ec];
    float v  = ei < end ? v0 : 0.f;
    if (act) {
      u32x4 u = (j < 4) ? *(const u32x4*)(xa + (size_t)s * XA_C + j * 8)
                        : *(const u32x4*)(xb + (size_t)s * XB_C);
      acc[0] = fmaf(v, bf2f(u.x & 0xffffu), acc[0]);
      acc[1] = fmaf(v, bf2f(u.x >> 16),     acc[1]);
      acc[2] = fmaf(v, bf2f(u.y & 0xffffu), acc[2]);
      acc[3] = fmaf(v, bf2f(u.y >> 16),     acc[3]);
      acc[4] = fmaf(v, bf2f(u.z & 0xffffu), acc[4]);
      acc[5] = fmaf(v, bf2f(u.z >> 16),     acc[5]);
      acc[6] = fmaf(v, bf2f(u.w & 0xffffu), acc[6]);
      acc[7] = fmaf(v, bf2f(u.w >> 16),     acc[7]);
    }
  }

  // reduce across the 8 edge slots (lane bits 3..5); partners share j
#pragma unroll
  for (int c = 0; c < 8; ++c) acc[c] += __shfl_xor(acc[c], 8);
#pragma unroll
  for (int c = 0; c < 8; ++c) acc[c] += __shfl_xor(acc[c], 16);
#pragma unroll
  for (int c = 0; c < 8; ++c) acc[c] += __shfl_xor(acc[c], 32);

  if (out_f32) {
    if (lane < 5) {                 // lanes 0..4: j=0..4 -> cols 0..39
      float4 o0 = {acc[0], acc[1], acc[2], acc[3]};
      float4 o1 = {acc[4], acc[5], acc[6], acc[7]};
      float* p = zf + (size_t)node * C_DIM + j * 8;
      *(float4*)(p + 0) = o0;
      *(float4*)(p + 4) = o1;
    }
  } else {
    if (lane < 5) {                 // lanes 0..4 write split layout
      uint4 p;
      p.x = (uint)f2bf(acc[0]) | ((uint)f2bf(acc[1]) << 16);
      p.y = (uint)f2bf(acc[2]) | ((uint)f2bf(acc[3]) << 16);
      p.z = (uint)f2bf(acc[4]) | ((uint)f2bf(acc[5]) << 16);
      p.w = (uint)f2bf(acc[6]) | ((uint)f2bf(acc[7]) << 16);
      if (j < 4) *(uint4*)(za + (size_t)node * XA_C + j * 8) = p;
      else       *(uint4*)(zb + (size_t)node * XB_C) = p;
    }
  }
}

// ---------------------------------------------------------------------------
extern "C" void kernel_launch(void* const* d_in, const int* in_sizes, int n_in,
                              void* d_out, int out_size, void* d_ws, size_t ws_size,
                              hipStream_t stream) {
  const float* feat  = (const float*)d_in[0];
  const float* W1    = (const float*)d_in[1];
  const float* W2    = (const float*)d_in[2];
  const int*   esrc  = (const int*)d_in[3];
  const int*   edst  = (const int*)d_in[4];
  const float* evalp = (const float*)d_in[5];
  float* out = (float*)d_out;

  const int N = in_sizes[0] / IN_DIM;   // 100000
  const int E = in_sizes[3];            // 1600000

  const int nblk = (N + BM - 1) / BM;   // GEMM1 blocks

  // ws: z0a [N][32] | z0b [N][8] | z1a [N][32] | z1b [N][8] | b_frag | w2f | row_ptr
  char* ws = (char*)d_ws;
  ushort* z0a    = (ushort*)ws;
  ushort* z0b    = z0a + (size_t)N * XA_C;
  ushort* z1a    = z0b + (size_t)N * XB_C;
  ushort* z1b    = z1a + (size_t)N * XA_C;
  ushort* b_frag = z1b + (size_t)N * XB_C;
  ushort* w2f    = b_frag + 4 * 16 * STEP;
  int* row_ptr   = (int*)(w2f + 16 * STEP);

  const int setup_items = E + 4096 + 1024;
  setup_kernel<<<(setup_items + 255) / 256, 256, 0, stream>>>(
      edst, E, row_ptr, N, W1, W2, b_frag, w2f);
  fused_dense_kernel<<<nblk, 256, 0, stream>>>(feat, b_frag, w2f, z0a, z0b, N);
  spmm_kernel<<<(N + 3) / 4, 256, 0, stream>>>(row_ptr, esrc, evalp, z0a, z0b,
                                               z1a, z1b, nullptr, N, 0);
  spmm_kernel<<<(N + 3) / 4, 256, 0, stream>>>(row_ptr, esrc, evalp, z1a, z1b,
                                               nullptr, nullptr, out, N, 1);
}

// Round 9
// 272.912 us; speedup vs baseline: 1.0318x; 1.0318x over previous
//
#include <hip/hip_runtime.h>
#include <cstddef>
#include <cstdint>

#define IN_DIM 256
#define H_DIM  128
#define C_DIM  40
#define BM     128
#define LDQ    68    // ushort stride of quarter-slab rows (136 B; 2-bank spread)
#define PAD_C  40    // z row width in bf16 cols: 40 cols = 80 B
#define STEP   512   // ushorts per ks slab of b_frag/w2f: 64 lanes x 8 bf16

typedef short bf16x8 __attribute__((ext_vector_type(8)));
typedef float f32x16 __attribute__((ext_vector_type(16)));
typedef uint  u32x4  __attribute__((ext_vector_type(4)));

__device__ __forceinline__ ushort f2bf(float f) {   // RNE fp32 -> bf16
  uint u = __builtin_bit_cast(uint, f);
  u += 0x7fffu + ((u >> 16) & 1u);
  return (ushort)(u >> 16);
}
__device__ __forceinline__ float bf2f(uint s) {     // low 16 bits -> f32
  uint u = s << 16;
  return __builtin_bit_cast(float, u);
}
// packed fp32x2 -> bf16x2 (HW cvt if available; manual RNE fallback)
__device__ __forceinline__ uint pack2bf(float a, float b) {
#if __has_builtin(__builtin_amdgcn_cvt_pk_bf16_f32)
  typedef __bf16 bf16v2 __attribute__((ext_vector_type(2)));
  bf16v2 r = __builtin_amdgcn_cvt_pk_bf16_f32(a, b);
  return __builtin_bit_cast(uint, r);
#else
  return (uint)f2bf(a) | ((uint)f2bf(b) << 16);
#endif
}

// ---------------------------------------------------------------------------
// Setup (one launch):
//  tid < E:     CSR row_ptr via boundary scan of sorted dst (coalesced O(E)).
//  next 4096:   W1 -> b_frag (MFMA B-fragment order for GEMM1).
//  next 1024:   W2 -> w2f   (MFMA B-fragment order for GEMM2, zero-pad n>=40).
// b_frag[tn][ks][l] (ushort8) = W1[16ks + (l>>5)*8 + j][32tn + (l&31)]
// w2f[kb][tn][l]    (ushort8) = W2[16kb + (l>>5)*8 + j][32tn + (l&31)] (0 pad)
// ---------------------------------------------------------------------------
__global__ void setup_kernel(const int* __restrict__ dst, int E,
                             int* __restrict__ row_ptr, int N,
                             const float* __restrict__ W1,
                             const float* __restrict__ W2,
                             ushort* __restrict__ b_frag,
                             ushort* __restrict__ w2f) {
  int tid = blockIdx.x * blockDim.x + threadIdx.x;
  if (tid < E) {
    int d1 = dst[tid];
    int d0 = (tid == 0) ? -1 : dst[tid - 1];
    for (int v = d0 + 1; v <= d1; ++v) row_ptr[v] = tid;
    if (tid == E - 1)
      for (int v = d1 + 1; v <= N; ++v) row_ptr[v] = E;
    return;
  }
  int u = tid - E;
  if (u < 4096) {                               // W1 -> b_frag fragment order
    int l = u & 63, ks = (u >> 6) & 15, tn = u >> 10;
    int n  = 32 * tn + (l & 31);
    int k0 = ks * 16 + ((l >> 5) << 3);
    ushort r[8];
#pragma unroll
    for (int j = 0; j < 8; ++j) r[j] = f2bf(W1[(k0 + j) * H_DIM + n]);
    *(uint4*)(b_frag + u * 8) = *(uint4*)r;
    return;
  }
  u -= 4096;
  if (u < 1024) {                               // W2 -> w2f fragment order
    int l = u & 63, kt = u >> 6;                // kt = kb*2 + tn
    int tn = kt & 1, kb = kt >> 1;
    int n  = 32 * tn + (l & 31);
    int k0 = kb * 16 + ((l >> 5) << 3);
    ushort r[8];
#pragma unroll
    for (int j = 0; j < 8; ++j)
      r[j] = (n < C_DIM) ? f2bf(W2[(k0 + j) * C_DIM + n]) : (ushort)0;
    *(uint4*)(w2f + u * 8) = *(uint4*)r;
  }
}

// ---------------------------------------------------------------------------
// Fused dense MLP: z0[n][0:40] = relu(feat[n] @ W1) @ W2, bf16, row stride 40.
// Block 256 thr (4 waves), 17408 B LDS -> ~5+ blocks/CU. ZERO BARRIERS;
// wave-private QUARTER slab (32 rows x 64 cols bf16, stride LDQ).
// KEY CHANGE vs R8 (which pinned at 59.5 us, all pipes <8% busy): staging
// loads are issued CONTINUOUSLY — during quarter q's 4 MFMA K-steps the wave
// issues quarter q+1's 8 loads (2 per K-step), ds_writing them at the quarter
// boundary (in-order LDS per wave = WAR-safe). Keeps 2-8 staging loads + B
// prefetch in flight at ALL times instead of burst-then-silence, raising the
// time-averaged outstanding bytes (Little's law) that capped reads at ~1 TB/s.
// Staging shape: lane = 16B of a 256-B row-chunk, 4 rows/instr, sector-exact.
// GEMM2 reuses the slab in two h-chunks (cols 0..63 -> kb 0..3, 64..127 -> 4..7).
// ---------------------------------------------------------------------------
__global__ __launch_bounds__(256, 4) void fused_dense_kernel(
    const float* __restrict__ feat, const ushort* __restrict__ b_frag,
    const ushort* __restrict__ w2f, ushort* __restrict__ z0, int N) {
  __shared__ __align__(16) ushort smem[4 * 32 * LDQ];   // 17408 B

  const int t = threadIdx.x;
  const int w = t >> 6, l = t & 63;
  const int nb = blockIdx.x * BM;
  ushort* slab = smem + w * (32 * LDQ);          // this wave's private region

  const int sr = l >> 4;                          // staging row-in-group 0..3
  const int sc = l & 15;                          // staging col quad (16 B)

  f32x16 acc[4];
#pragma unroll
  for (int tn = 0; tn < 4; ++tn)
#pragma unroll
    for (int r = 0; r < 16; ++r) acc[tn][r] = 0.f;

  const ushort* bp = b_frag + l * 8;
  bf16x8 Bx[2][4];
#pragma unroll
  for (int tn = 0; tn < 4; ++tn)
    Bx[0][tn] = *(const bf16x8*)(bp + tn * (16 * STEP));

  // per-lane staging base: row = nb+32w+4c+sr, col = q*64 + sc*4
  const float* fbase = feat + (size_t)(nb + 32 * w) * IN_DIM + sc * 4;

  float4 pre[8];
  // prologue: load quarter 0 (8 chunks; chunk c covers rows 4c..4c+3, 256 B each)
#pragma unroll
  for (int c = 0; c < 8; ++c) {
    int grow = nb + 32 * w + 4 * c + sr;
    const float* p = fbase + (size_t)(4 * c + sr) * IN_DIM;
    if (grow >= N) p = feat + (size_t)(N - 1) * IN_DIM + sc * 4;
    pre[c] = *(const float4*)(p);
  }
#pragma unroll
  for (int c = 0; c < 8; ++c) {
    uint2 pk;
    pk.x = pack2bf(pre[c].x, pre[c].y);
    pk.y = pack2bf(pre[c].z, pre[c].w);
    *(uint2*)(slab + (4 * c + sr) * LDQ + sc * 4) = pk;
  }

  const ushort* Abase = slab + (l & 31) * LDQ + ((l >> 5) << 3);

#pragma unroll
  for (int q = 0; q < 4; ++q) {
#pragma unroll
    for (int ks = 0; ks < 4; ++ks) {
      const int gks = 4 * q + ks;
      const int c = gks & 1;
      if (gks < 15) {                            // B depth-1 ping-pong (L2)
#pragma unroll
        for (int tn = 0; tn < 4; ++tn)
          Bx[c ^ 1][tn] = *(const bf16x8*)(bp + tn * (16 * STEP) + (gks + 1) * STEP);
      }
      if (q < 3) {                               // 2 staging loads of quarter q+1
#pragma unroll
        for (int d = 0; d < 2; ++d) {
          const int cc = 2 * ks + d;
          int grow = nb + 32 * w + 4 * cc + sr;
          const float* p = fbase + (size_t)(4 * cc + sr) * IN_DIM + (q + 1) * 64;
          if (grow >= N) p = feat + (size_t)(N - 1) * IN_DIM + sc * 4 + (q + 1) * 64;
          pre[cc] = *(const float4*)(p);
        }
      }
      bf16x8 af = *(const bf16x8*)(Abase + ks * 16);
#pragma unroll
      for (int tn = 0; tn < 4; ++tn)
        acc[tn] = __builtin_amdgcn_mfma_f32_32x32x16_bf16(af, Bx[c][tn], acc[tn], 0, 0, 0);
    }
    if (q < 3) {                                 // quarter boundary: write q+1
#pragma unroll
      for (int c = 0; c < 8; ++c) {
        uint2 pk;
        pk.x = pack2bf(pre[c].x, pre[c].y);
        pk.y = pack2bf(pre[c].z, pre[c].w);
        *(uint2*)(slab + (4 * c + sr) * LDQ + sc * 4) = pk;
      }
    }
  }

  // ---- GEMM2 over two h-chunks reusing the quarter slab (zero barriers)
  f32x16 acc2[2];
#pragma unroll
  for (int tn = 0; tn < 2; ++tn)
#pragma unroll
    for (int r = 0; r < 16; ++r) acc2[tn][r] = 0.f;

  const ushort* Hbase = slab + (l & 31) * LDQ + ((l >> 5) << 3);
  const ushort* wp = w2f + l * 8;

#pragma unroll
  for (int hc = 0; hc < 2; ++hc) {
    // relu(h) chunk hc: cols 64*hc .. 64*hc+63 -> slab cols 0..63
#pragma unroll
    for (int tn = 2 * hc; tn < 2 * hc + 2; ++tn) {
      int col = (tn - 2 * hc) * 32 + (l & 31);
#pragma unroll
      for (int r = 0; r < 16; ++r) {
        int nl = (r & 3) + 8 * (r >> 2) + 4 * (l >> 5);
        float v = acc[tn][r];
        slab[nl * LDQ + col] = f2bf(v > 0.f ? v : 0.f);
      }
    }
#pragma unroll
    for (int kb = 4 * hc; kb < 4 * hc + 4; ++kb) {
      bf16x8 af = *(const bf16x8*)(Hbase + (kb - 4 * hc) * 16);
#pragma unroll
      for (int tn = 0; tn < 2; ++tn) {
        bf16x8 bfr = *(const bf16x8*)(wp + (kb * 2 + tn) * STEP);
        acc2[tn] = __builtin_amdgcn_mfma_f32_32x32x16_bf16(af, bfr, acc2[tn], 0, 0, 0);
      }
    }
  }

  // store z0 cols 0..39 only (row stride PAD_C = 40)
#pragma unroll
  for (int tn = 0; tn < 2; ++tn) {
    int col = tn * 32 + (l & 31);
    if (col < C_DIM) {
#pragma unroll
      for (int r = 0; r < 16; ++r) {
        int node = nb + 32 * w + (r & 3) + 8 * (r >> 2) + 4 * (l >> 5);
        if (node < N) z0[(size_t)node * PAD_C + col] = f2bf(acc2[tn][r]);
      }
    }
  }
}

// ---------------------------------------------------------------------------
// SPMM (CSR, dst-sorted): one wave per node. lane = 8*h + j (h = edge slot,
// j = col oct). Rows are 40 bf16 cols = 80 B -> only lanes with j < 5
// gather/FMA. Main loop unrolled x2 (16 edges/iter). Butterfly-reduce slots.
// (R7 form — split-x of R8 regressed ~8 us, reverted.)
// ---------------------------------------------------------------------------
__global__ __launch_bounds__(256) void spmm_kernel(
    const int* __restrict__ row_ptr, const int* __restrict__ esrc,
    const float* __restrict__ eval, const ushort* __restrict__ x,
    ushort* __restrict__ zb, float* __restrict__ zf, int N, int out_f32) {
  int node = (blockIdx.x << 2) + (threadIdx.x >> 6);
  if (node >= N) return;
  const int lane = threadIdx.x & 63;
  const int h = lane >> 3;          // edge slot
  const int j = lane & 7;           // col oct: cols 8j..8j+7 (j<5 active)
  const bool act = (j < 5);

  int e   = row_ptr[node];
  int end = row_ptr[node + 1];

  float acc[8];
#pragma unroll
  for (int c = 0; c < 8; ++c) acc[c] = 0.f;

  // 16 edges per iteration: two independent gather chains
  for (; e + 16 <= end; e += 16) {
    int   s0 = esrc[e + h];
    int   s1 = esrc[e + 8 + h];
    float v0 = eval[e + h];
    float v1 = eval[e + 8 + h];
    if (act) {
      u32x4 a = *(const u32x4*)(x + (size_t)s0 * PAD_C + j * 8);
      u32x4 b = *(const u32x4*)(x + (size_t)s1 * PAD_C + j * 8);
      acc[0] = fmaf(v0, bf2f(a.x & 0xffffu), acc[0]);
      acc[1] = fmaf(v0, bf2f(a.x >> 16),     acc[1]);
      acc[2] = fmaf(v0, bf2f(a.y & 0xffffu), acc[2]);
      acc[3] = fmaf(v0, bf2f(a.y >> 16),     acc[3]);
      acc[4] = fmaf(v0, bf2f(a.z & 0xffffu), acc[4]);
      acc[5] = fmaf(v0, bf2f(a.z >> 16),     acc[5]);
      acc[6] = fmaf(v0, bf2f(a.w & 0xffffu), acc[6]);
      acc[7] = fmaf(v0, bf2f(a.w >> 16),     acc[7]);
      acc[0] = fmaf(v1, bf2f(b.x & 0xffffu), acc[0]);
      acc[1] = fmaf(v1, bf2f(b.x >> 16),     acc[1]);
      acc[2] = fmaf(v1, bf2f(b.y & 0xffffu), acc[2]);
      acc[3] = fmaf(v1, bf2f(b.y >> 16),     acc[3]);
      acc[4] = fmaf(v1, bf2f(b.z & 0xffffu), acc[4]);
      acc[5] = fmaf(v1, bf2f(b.z >> 16),     acc[5]);
      acc[6] = fmaf(v1, bf2f(b.w & 0xffffu), acc[6]);
      acc[7] = fmaf(v1, bf2f(b.w >> 16),     acc[7]);
    }
  }
  for (; e + 8 <= end; e += 8) {
    int   s = esrc[e + h];
    float v = eval[e + h];
    if (act) {
      u32x4 u = *(const u32x4*)(x + (size_t)s * PAD_C + j * 8);
      acc[0] = fmaf(v, bf2f(u.x & 0xffffu), acc[0]);
      acc[1] = fmaf(v, bf2f(u.x >> 16),     acc[1]);
      acc[2] = fmaf(v, bf2f(u.y & 0xffffu), acc[2]);
      acc[3] = fmaf(v, bf2f(u.y >> 16),     acc[3]);
      acc[4] = fmaf(v, bf2f(u.z & 0xffffu), acc[4]);
      acc[5] = fmaf(v, bf2f(u.z >> 16),     acc[5]);
      acc[6] = fmaf(v, bf2f(u.w & 0xffffu), acc[6]);
      acc[7] = fmaf(v, bf2f(u.w >> 16),     acc[7]);
    }
  }
  if (e < end) {                    // tail: clamp slots past the end, weight 0
    int ei = e + h;
    int ec = ei < end ? ei : end - 1;
    int   s  = esrc[ec];
    float v0 = eval[ec];
    float v  = ei < end ? v0 : 0.f;
    if (act) {
      u32x4 u = *(const u32x4*)(x + (size_t)s * PAD_C + j * 8);
      acc[0] = fmaf(v, bf2f(u.x & 0xffffu), acc[0]);
      acc[1] = fmaf(v, bf2f(u.x >> 16),     acc[1]);
      acc[2] = fmaf(v, bf2f(u.y & 0xffffu), acc[2]);
      acc[3] = fmaf(v, bf2f(u.y >> 16),     acc[3]);
      acc[4] = fmaf(v, bf2f(u.z & 0xffffu), acc[4]);
      acc[5] = fmaf(v, bf2f(u.z >> 16),     acc[5]);
      acc[6] = fmaf(v, bf2f(u.w & 0xffffu), acc[6]);
      acc[7] = fmaf(v, bf2f(u.w >> 16),     acc[7]);
    }
  }

  // reduce across the 8 edge slots (lane bits 3..5); partners share j
#pragma unroll
  for (int c = 0; c < 8; ++c) acc[c] += __shfl_xor(acc[c], 8);
#pragma unroll
  for (int c = 0; c < 8; ++c) acc[c] += __shfl_xor(acc[c], 16);
#pragma unroll
  for (int c = 0; c < 8; ++c) acc[c] += __shfl_xor(acc[c], 32);

  if (out_f32) {
    if (lane < 5) {                 // lanes 0..4: j=0..4 -> cols 0..39
      float4 o0 = {acc[0], acc[1], acc[2], acc[3]};
      float4 o1 = {acc[4], acc[5], acc[6], acc[7]};
      float* p = zf + (size_t)node * C_DIM + j * 8;
      *(float4*)(p + 0) = o0;
      *(float4*)(p + 4) = o1;
    }
  } else {
    if (lane < 5) {                 // lanes 0..4: j=0..4 -> cols 0..39
      uint4 p;
      p.x = (uint)f2bf(acc[0]) | ((uint)f2bf(acc[1]) << 16);
      p.y = (uint)f2bf(acc[2]) | ((uint)f2bf(acc[3]) << 16);
      p.z = (uint)f2bf(acc[4]) | ((uint)f2bf(acc[5]) << 16);
      p.w = (uint)f2bf(acc[6]) | ((uint)f2bf(acc[7]) << 16);
      *(uint4*)(zb + (size_t)node * PAD_C + j * 8) = p;
    }
  }
}

// ---------------------------------------------------------------------------
extern "C" void kernel_launch(void* const* d_in, const int* in_sizes, int n_in,
                              void* d_out, int out_size, void* d_ws, size_t ws_size,
                              hipStream_t stream) {
  const float* feat  = (const float*)d_in[0];
  const float* W1    = (const float*)d_in[1];
  const float* W2    = (const float*)d_in[2];
  const int*   esrc  = (const int*)d_in[3];
  const int*   edst  = (const int*)d_in[4];
  const float* evalp = (const float*)d_in[5];
  float* out = (float*)d_out;

  const int N = in_sizes[0] / IN_DIM;   // 100000
  const int E = in_sizes[3];            // 1600000

  const int nblk = (N + BM - 1) / BM;   // GEMM1 blocks

  // ws: z0 bf16 [N][40] | z1 bf16 [N][40] | b_frag (64 KB) | w2f (16 KB) | row_ptr
  char* ws = (char*)d_ws;
  ushort* z0     = (ushort*)ws;
  ushort* z1     = (ushort*)(ws + (size_t)N * PAD_C * 2);
  ushort* b_frag = (ushort*)(ws + (size_t)N * PAD_C * 4);
  ushort* w2f    = b_frag + 4 * 16 * STEP;
  int* row_ptr   = (int*)(w2f + 16 * STEP);

  const int setup_items = E + 4096 + 1024;
  setup_kernel<<<(setup_items + 255) / 256, 256, 0, stream>>>(
      edst, E, row_ptr, N, W1, W2, b_frag, w2f);
  fused_dense_kernel<<<nblk, 256, 0, stream>>>(feat, b_frag, w2f, z0, N);
  spmm_kernel<<<(N + 3) / 4, 256, 0, stream>>>(row_ptr, esrc, evalp, z0, z1, nullptr, N, 0);
  spmm_kernel<<<(N + 3) / 4, 256, 0, stream>>>(row_ptr, esrc, evalp, z1, nullptr, out, N, 1);
}